// Round 21
// baseline (499.331 us; speedup 1.0000x reference)
//
#include <hip/hip_runtime.h>
#include <stdint.h>

typedef int i32x4 __attribute__((ext_vector_type(4)));
typedef unsigned short u16x8 __attribute__((ext_vector_type(8)));

#define N_TOK 2048
#define HID   4096
#define INTER 11008
#define TWOI  22016
#define KT1   64     // HID/64   k-steps for gemm1
#define KT2   172    // INTER/64 k-steps for gemm2

__device__ __forceinline__ unsigned short f2bf(float f) {
  uint32_t u = __float_as_uint(f);
  uint32_t r = (u + 0x7fffu + ((u >> 16) & 1u)) >> 16;
  return (unsigned short)r;
}

__device__ __forceinline__ float bf2f(unsigned short b) {
  return __uint_as_float(((uint32_t)b) << 16);
}

// ---------------------------------------------------------------------------
// pack_frag: int32 [R][K] -> int8 FRAGMENT-MAJOR panels
//   [p][kt][frag f][lane l][16B]: byte(f,l) = src[p*PR + f*16 + (l&15)]
//   [kt*64 + (l>>4)*16 .. +15]. A wave's fragment load (lane l at
//   f*1024 + l*16) is 1024 CONTIGUOUS bytes -> perfectly coalesced
//   global_load_dwordx4, enabling direct-to-register GEMM operands.
// ---------------------------------------------------------------------------
__global__ __launch_bounds__(256) void pack_frag(
    const int* __restrict__ src, uint8_t* __restrict__ dst,
    int lgPR, int KT, int K)
{
  const int u = blockIdx.x * 256 + threadIdx.x;
  const int l = u & 63;
  const int rest = u >> 6;
  const int f = rest & ((1 << (lgPR - 4)) - 1);
  const int s = rest >> (lgPR - 4);
  const int p = s / KT;
  const int kt = s - p * KT;
  const int row = (p << lgPR) + f * 16 + (l & 15);
  const int col = kt * 64 + ((l >> 4) << 4);
  const int* sp = src + (size_t)row * K + col;
  i32x4 o;
#pragma unroll
  for (int qq = 0; qq < 4; ++qq) {
    i32x4 w = *reinterpret_cast<const i32x4*>(sp + qq * 4);
    o[qq] = (w[0] & 255) | ((w[1] & 255) << 8) | ((w[2] & 255) << 16)
          | ((w[3] & 255) << 24);
  }
  *reinterpret_cast<i32x4*>(dst + (size_t)u * 16) = o;
}

// ---------------------------------------------------------------------------
// pack_gufrag: w_gateup int32 [2I][H] -> frag-major panels [86][KT1][16f][64l]
// with gate/up INTERLEAVED at fragment granularity:
//   frag 2j = gate rows ntB*128+16j..+15, frag 2j+1 = matching up rows.
// acc[m][2p] (gate) and acc[m][2p+1] (up) then pair in registers.
// ---------------------------------------------------------------------------
__global__ __launch_bounds__(256) void pack_gufrag(
    const int* __restrict__ src, uint8_t* __restrict__ dst)
{
  const int u = blockIdx.x * 256 + threadIdx.x;
  const int l = u & 63;
  const int rest = u >> 6;
  const int fi = rest & 15;
  const int s = rest >> 4;
  const int p = s / KT1;
  const int kt = s - p * KT1;
  const int base = p * 128 + ((fi >> 1) << 4) + (l & 15);
  const int srow = (fi & 1) ? (INTER + base) : base;
  const int col = kt * 64 + ((l >> 4) << 4);
  const int* sp = src + (size_t)srow * HID + col;
  i32x4 o;
#pragma unroll
  for (int qq = 0; qq < 4; ++qq) {
    i32x4 w = *reinterpret_cast<const i32x4*>(sp + qq * 4);
    o[qq] = (w[0] & 255) | ((w[1] & 255) << 8) | ((w[2] & 255) << 16)
          | ((w[3] & 255) << 24);
  }
  *reinterpret_cast<i32x4*>(dst + (size_t)u * 16) = o;
}

__global__ __launch_bounds__(1024) void zero_mx(float* __restrict__ mx) {
  const int i = blockIdx.x * 1024 + threadIdx.x;
  if (i < N_TOK) mx[i] = 0.0f;
}

// ---------------------------------------------------------------------------
// GEMM1, DIRECT-TO-REGISTER: 256x256 tile, 8 waves (2Mx4N, wave 128x64).
// No LDS operand staging, NO K-loop barriers: each wave streams its own
// coalesced fragments global->VGPR, double-buffered (named sets; compiler
// emits counted vmcnt on first use). VMEM pipe overlaps MFMA pipe natively;
// waves de-phase (setprio meaningful). Redundant cross-wave reads are
// absorbed by L1/L2/LLC (panels are LLC-resident).
// Epilogue: in-register silu(g)*u -> act bf16; rowmax via shfl + 4KB LDS
// cross-wave reduce -> one atomicMax per row per block (r20).
// ---------------------------------------------------------------------------
__global__ __launch_bounds__(512, 2) void gemm1_k(
    const uint8_t* __restrict__ x8p, const uint8_t* __restrict__ wgp,
    const float* __restrict__ xs, const float* __restrict__ wgs,
    unsigned short* __restrict__ act, float* __restrict__ mx)
{
  __shared__ float smred[1024];          // 4KB cross-wave rowmax reduce
  const int tid = threadIdx.x;
  const int lane = tid & 63, wid = tid >> 6;
  const int wgm = wid >> 2, wgn = wid & 3;
  const int r15 = lane & 15;
  const int l16 = lane * 16;

  const int bid = blockIdx.x;
  const int v = (bid & 7) * 86 + (bid >> 3);   // 688 = 8*86, bijective
  const int mt = v & 7;                        // 8 M-tiles of 256
  const int ntB = v >> 3;                      // 86 act-col tiles of 128

  const uint8_t* pA = x8p + (size_t)mt  * (KT1 * 16384) + (wgm << 13) + l16;
  const uint8_t* pB = wgp + (size_t)ntB * (KT1 * 16384) + (wgn << 12) + l16;

  i32x4 acc[8][4] = {};
  i32x4 aA[8], bA[4], aB[8], bB[4];

#define LD1(AS, BS, t) do {                                          \
    const uint8_t* ap_ = pA + (size_t)(t) * 16384;                   \
    const uint8_t* bp_ = pB + (size_t)(t) * 16384;                   \
    _Pragma("unroll")                                                \
    for (int m = 0; m < 8; ++m)                                      \
      AS[m] = *reinterpret_cast<const i32x4*>(ap_ + m * 1024);       \
    _Pragma("unroll")                                                \
    for (int n = 0; n < 4; ++n)                                      \
      BS[n] = *reinterpret_cast<const i32x4*>(bp_ + n * 1024);       \
  } while (0)

#define MM1(AS, BS) do {                                             \
    __builtin_amdgcn_s_setprio(1);                                   \
    _Pragma("unroll")                                                \
    for (int m = 0; m < 8; ++m)                                      \
      _Pragma("unroll")                                              \
      for (int n = 0; n < 4; ++n)                                    \
        acc[m][n] = __builtin_amdgcn_mfma_i32_16x16x64_i8(           \
            AS[m], BS[n], acc[m][n], 0, 0, 0);                       \
    __builtin_amdgcn_s_setprio(0);                                   \
  } while (0)

  LD1(aA, bA, 0);
#pragma unroll 1
  for (int t = 0; t < KT1; t += 2) {
    if (t + 1 < KT1) LD1(aB, bB, t + 1);
    MM1(aA, bA);
    if (t + 2 < KT1) LD1(aA, bA, t + 2);
    MM1(aB, bB);
  }
#undef LD1
#undef MM1

  // ---- fused epilogue: silu(gate)*up in registers + rowmax ----
  // acc[m][2p]=gate(row,col p), acc[m][2p+1]=up(row,col p);
  // col = ntB*128 + wgn*32 + p*16 + r15.
  const int rq = (lane >> 4) << 2;
#pragma unroll
  for (int m = 0; m < 8; ++m) {
    float am[4] = {0.f, 0.f, 0.f, 0.f};
#pragma unroll
    for (int p = 0; p < 2; ++p) {
      const int colb = ntB * 128 + (wgn << 5) + (p << 4) + r15;
      const float gsc = wgs[colb];
      const float usc = wgs[INTER + colb];
#pragma unroll
      for (int r = 0; r < 4; ++r) {
        const int rowl = (wgm << 7) + m * 16 + rq + r;
        const int grow = mt * 256 + rowl;
        const float xr = xs[grow];
        const float g  = (float)acc[m][2 * p][r] * xr * gsc;
        const float uv = (float)acc[m][2 * p + 1][r] * xr * usc;
        const float a  = g / (1.f + __expf(-g)) * uv;
        act[(size_t)grow * INTER + colb] = f2bf(a);
        am[r] = fmaxf(am[r], __builtin_fabsf(a));
      }
    }
#pragma unroll
    for (int r = 0; r < 4; ++r)
#pragma unroll
      for (int off = 1; off < 16; off <<= 1)
        am[r] = fmaxf(am[r], __shfl_xor(am[r], off, 64));
    if (r15 == 0) {
#pragma unroll
      for (int r = 0; r < 4; ++r)
        smred[wgn * 256 + (wgm << 7) + m * 16 + rq + r] = am[r];
    }
  }
  __syncthreads();
  if (tid < 256) {
    const float vmx = fmaxf(fmaxf(smred[tid], smred[256 + tid]),
                            fmaxf(smred[512 + tid], smred[768 + tid]));
    atomicMax((int*)&mx[mt * 256 + tid], __float_as_int(vmx));
  }
}

// ---------------------------------------------------------------------------
// quant: q2 = clip(rint(act * 127/mx)) -> int8 FRAGMENT-MAJOR panel
// (PR=128, 8 frags/step, 16 panels x KT2 steps). No silu recompute.
// ---------------------------------------------------------------------------
__global__ __launch_bounds__(256) void quant_k(
    const unsigned short* __restrict__ act, const float* __restrict__ mx,
    uint8_t* __restrict__ q2p)
{
  const int u = blockIdx.x * 256 + threadIdx.x;
  const int l = u & 63;
  const int rest = u >> 6;
  const int f = rest & 7;                // 8 frags (PR=128)
  const int s = rest >> 3;
  const int mt = s / KT2;
  const int t = s - mt * KT2;
  const int row = mt * 128 + f * 16 + (l & 15);
  const int col = t * 64 + ((l >> 4) << 4);
  const unsigned short* ap = act + (size_t)row * INTER + col;
  const float inv = 127.0f / fmaxf(mx[row], 1e-30f);
  u16x8 a0 = *reinterpret_cast<const u16x8*>(ap);
  u16x8 a1 = *reinterpret_cast<const u16x8*>(ap + 8);
  i32x4 o;
#pragma unroll
  for (int qq = 0; qq < 4; ++qq) {
    uint32_t d = 0;
#pragma unroll
    for (int b = 0; b < 4; ++b) {
      const int j = qq * 4 + b;
      float af = bf2f((j < 8) ? a0[j] : a1[j - 8]);
      float rr = rintf(af * inv);
      rr = fminf(fmaxf(rr, -127.f), 127.f);
      d |= ((uint32_t)((int)rr & 255)) << (8 * b);
    }
    o[qq] = (int)d;
  }
  *reinterpret_cast<i32x4*>(q2p + (size_t)u * 16) = o;
}

// ---------------------------------------------------------------------------
// GEMM2, DIRECT-TO-REGISTER: 128x256 tile, 8 waves (2Mx4N, wave 64x64).
// No LDS, no barriers: fragment streams global->VGPR, double-buffered.
// out[row][col] = acc * (mx[row]/127) * wds[col], f32.
// ---------------------------------------------------------------------------
__global__ __launch_bounds__(512, 2) void gemm2_k(
    const uint8_t* __restrict__ q2p, const uint8_t* __restrict__ wdp,
    const float* __restrict__ mx, const float* __restrict__ wds,
    float* __restrict__ out)
{
  const int tid = threadIdx.x;
  const int lane = tid & 63, wid = tid >> 6;
  const int wgm = wid >> 2, wgn = wid & 3;
  const int r15 = lane & 15;
  const int l16 = lane * 16;

  const int bid = blockIdx.x;
  const int v = (bid & 7) * 32 + (bid >> 3);   // XCD-chunked, bijective
  const int nt = v >> 4, mt = v & 15;

  const uint8_t* pA = q2p + (size_t)mt * (KT2 * 8192)  + (wgm << 12) + l16;
  const uint8_t* pB = wdp + (size_t)nt * (KT2 * 16384) + (wgn << 12) + l16;

  i32x4 acc[4][4] = {};
  i32x4 aA[4], bA[4], aB[4], bB[4];

#define LD2(AS, BS, t) do {                                          \
    const uint8_t* ap_ = pA + (size_t)(t) * 8192;                    \
    const uint8_t* bp_ = pB + (size_t)(t) * 16384;                   \
    _Pragma("unroll")                                                \
    for (int m = 0; m < 4; ++m)                                      \
      AS[m] = *reinterpret_cast<const i32x4*>(ap_ + m * 1024);       \
    _Pragma("unroll")                                                \
    for (int n = 0; n < 4; ++n)                                      \
      BS[n] = *reinterpret_cast<const i32x4*>(bp_ + n * 1024);       \
  } while (0)

#define MM2(AS, BS) do {                                             \
    __builtin_amdgcn_s_setprio(1);                                   \
    _Pragma("unroll")                                                \
    for (int m = 0; m < 4; ++m)                                      \
      _Pragma("unroll")                                              \
      for (int n = 0; n < 4; ++n)                                    \
        acc[m][n] = __builtin_amdgcn_mfma_i32_16x16x64_i8(           \
            AS[m], BS[n], acc[m][n], 0, 0, 0);                       \
    __builtin_amdgcn_s_setprio(0);                                   \
  } while (0)

  LD2(aA, bA, 0);
#pragma unroll 1
  for (int t = 0; t < KT2; t += 2) {
    if (t + 1 < KT2) LD2(aB, bB, t + 1);
    MM2(aA, bA);
    if (t + 2 < KT2) LD2(aA, bA, t + 2);
    MM2(aB, bB);
  }
#undef LD2
#undef MM2

  const int rq = (lane >> 4) << 2;
#pragma unroll
  for (int m = 0; m < 4; ++m) {
#pragma unroll
    for (int r = 0; r < 4; ++r) {
      const int rowl = (wgm << 6) + m * 16 + rq + r;
      const int grow = mt * 128 + rowl;
      const float s2 = mx[grow] * (1.0f / 127.0f);
      float* op = out + (size_t)grow * HID + nt * 256 + (wgn << 6) + r15;
      const float* wp = wds + nt * 256 + (wgn << 6) + r15;
#pragma unroll
      for (int n = 0; n < 4; ++n)
        op[n * 16] = (float)acc[m][n][r] * s2 * wp[n * 16];
    }
  }
}

// ---------------------------------------------------------------------------
extern "C" void kernel_launch(void* const* d_in, const int* in_sizes, int n_in,
                              void* d_out, int out_size, void* d_ws, size_t ws_size,
                              hipStream_t stream)
{
  const int*   x_q = (const int*)d_in[0];
  const float* xs  = (const float*)d_in[1];
  const int*   wg  = (const int*)d_in[2];
  const float* wgs = (const float*)d_in[3];
  const int*   wd  = (const int*)d_in[4];
  const float* wds = (const float*)d_in[5];
  float* out = (float*)d_out;

  uint8_t* ws = (uint8_t*)d_ws;
  uint8_t* x8p = ws;                                         //   8,388,608
  uint8_t* wgp = x8p + 8388608;                              //  90,177,536
  uint8_t* wdp = wgp + 90177536;                             //  45,088,768
  unsigned short* act = (unsigned short*)(wdp + 45088768);   //  45,088,768
  float* mx = (float*)((uint8_t*)act + 45088768);            //       8,192
  uint8_t* q2p = (uint8_t*)mx + 8192;                        //  22,544,384
  // total ~211.3 MB

  zero_mx<<<2, 1024, 0, stream>>>(mx);
  pack_frag<<<2048, 256, 0, stream>>>(x_q, x8p, 8, KT1, HID);    // A panels
  pack_gufrag<<<22016, 256, 0, stream>>>(wg, wgp);               // B1 interleaved
  pack_frag<<<11008, 256, 0, stream>>>(wd, wdp, 8, KT2, INTER);  // B2 panels

  gemm1_k<<<688, 512, 0, stream>>>(x8p, wgp, xs, wgs, act, mx);
  quant_k<<<5504, 256, 0, stream>>>(act, mx, q2p);
  gemm2_k<<<256, 512, 0, stream>>>(q2p, wdp, mx, wds, out);
}

// Round 22
// 423.996 us; speedup vs baseline: 1.1777x; 1.1777x over previous
//
#include <hip/hip_runtime.h>
#include <stdint.h>

typedef int i32x4 __attribute__((ext_vector_type(4)));
typedef unsigned short u16x8 __attribute__((ext_vector_type(8)));

#define N_TOK 2048
#define HID   4096
#define INTER 11008
#define TWOI  22016
#define KT1   64     // HID/64   k-steps for gemm1
#define KT2   172    // INTER/64 k-steps for gemm2

#define GLD16(gp, lp) __builtin_amdgcn_global_load_lds( \
    (const __attribute__((address_space(1))) void*)(gp), \
    (__attribute__((address_space(3))) void*)(lp), 16, 0, 0)
#define BAR() __builtin_amdgcn_s_barrier()
#define WVM(n) asm volatile("s_waitcnt vmcnt(" #n ")" ::: "memory")
// rule #18: lgkmcnt asm must be followed by sched_barrier(0).
#define LGKM0() do { asm volatile("s_waitcnt lgkmcnt(0)" ::: "memory"); \
                     __builtin_amdgcn_sched_barrier(0); } while (0)

__device__ __forceinline__ unsigned short f2bf(float f) {
  uint32_t u = __float_as_uint(f);
  uint32_t r = (u + 0x7fffu + ((u >> 16) & 1u)) >> 16;
  return (unsigned short)r;
}

__device__ __forceinline__ float bf2f(unsigned short b) {
  return __uint_as_float(((uint32_t)b) << 16);
}

// ---------------------------------------------------------------------------
// pack_frag: int32 [R][K] -> int8 FRAGMENT-MAJOR panels
//   [p][kt][frag f][lane l][16B]: byte(f,l) = src[p*PR + f*16 + (l&15)]
//   [kt*64 + (l>>4)*16 .. +15]. Fragment ds_read_b128 = 1024 contiguous
//   bytes -> zero bank conflicts; global_load_lds staging stays linear.
// ---------------------------------------------------------------------------
__global__ __launch_bounds__(256) void pack_frag(
    const int* __restrict__ src, uint8_t* __restrict__ dst,
    int lgPR, int KT, int K)
{
  const int u = blockIdx.x * 256 + threadIdx.x;
  const int l = u & 63;
  const int rest = u >> 6;
  const int f = rest & ((1 << (lgPR - 4)) - 1);
  const int s = rest >> (lgPR - 4);
  const int p = s / KT;
  const int kt = s - p * KT;
  const int row = (p << lgPR) + f * 16 + (l & 15);
  const int col = kt * 64 + ((l >> 4) << 4);
  const int* sp = src + (size_t)row * K + col;
  i32x4 o;
#pragma unroll
  for (int qq = 0; qq < 4; ++qq) {
    i32x4 w = *reinterpret_cast<const i32x4*>(sp + qq * 4);
    o[qq] = (w[0] & 255) | ((w[1] & 255) << 8) | ((w[2] & 255) << 16)
          | ((w[3] & 255) << 24);
  }
  *reinterpret_cast<i32x4*>(dst + (size_t)u * 16) = o;
}

// ---------------------------------------------------------------------------
// pack_gufrag: w_gateup int32 [2I][H] -> frag-major panels [86][KT1][16f][64l]
// with gate/up INTERLEAVED at fragment granularity:
//   frag 2j   = gate rows  ntB*128 + 16j .. +15
//   frag 2j+1 = up rows    INTER + ntB*128 + 16j .. +15
// -> in gemm1, acc[m][2p] (gate) and acc[m][2p+1] (up) hold the SAME
// (row, act-col) pair in registers: silu fusion needs no cross-wave exchange.
// ---------------------------------------------------------------------------
__global__ __launch_bounds__(256) void pack_gufrag(
    const int* __restrict__ src, uint8_t* __restrict__ dst)
{
  const int u = blockIdx.x * 256 + threadIdx.x;
  const int l = u & 63;
  const int rest = u >> 6;
  const int fi = rest & 15;
  const int s = rest >> 4;
  const int p = s / KT1;
  const int kt = s - p * KT1;
  const int base = p * 128 + ((fi >> 1) << 4) + (l & 15);
  const int srow = (fi & 1) ? (INTER + base) : base;
  const int col = kt * 64 + ((l >> 4) << 4);
  const int* sp = src + (size_t)srow * HID + col;
  i32x4 o;
#pragma unroll
  for (int qq = 0; qq < 4; ++qq) {
    i32x4 w = *reinterpret_cast<const i32x4*>(sp + qq * 4);
    o[qq] = (w[0] & 255) | ((w[1] & 255) << 8) | ((w[2] & 255) << 16)
          | ((w[3] & 255) << 24);
  }
  *reinterpret_cast<i32x4*>(dst + (size_t)u * 16) = o;
}

__global__ __launch_bounds__(1024) void zero_mx(float* __restrict__ mx) {
  const int i = blockIdx.x * 1024 + threadIdx.x;
  if (i < N_TOK) mx[i] = 0.0f;
}

// ---------------------------------------------------------------------------
// GEMM1 (r18-frozen K-loop): 256x256 tile, 8 waves (2Mx4N, wave 128x64),
// BK=64B, 4-slot 32KB ring (128KB LDS), distance-3, vmcnt 8/4/0, 2-phase
// K-step, fragment-major LDS (zero-conflict reads). B = interleaved gate/up
// frags. Epilogue: in-register silu(g)*u -> act bf16 [N][I]; rowmax via
// 16-lane shfl + cross-wave LDS reduce -> ONE atomicMax per row per block.
// ---------------------------------------------------------------------------
__global__ __launch_bounds__(512, 2) void gemm1_k(
    const uint8_t* __restrict__ x8p, const uint8_t* __restrict__ wgp,
    const float* __restrict__ xs, const float* __restrict__ wgs,
    unsigned short* __restrict__ act, float* __restrict__ mx)
{
  __shared__ uint8_t sm[131072];         // 4 slots x (A 16KB + B 16KB)
  const int tid = threadIdx.x;
  const int lane = tid & 63, wid = tid >> 6;
  const int wgm = wid >> 2, wgn = wid & 3;
  const int r15 = lane & 15;
  const int l16 = lane * 16;
  const int aBase = (wgm << 13) + l16;            // wgm*8192
  const int bBase = 16384 + (wgn << 12) + l16;    // 16384 + wgn*4096

  const int bid = blockIdx.x;
  const int v = (bid & 7) * 86 + (bid >> 3);   // 688 = 8*86, bijective
  const int mt = v & 7;                        // 8 M-tiles of 256
  const int ntB = v >> 3;                      // 86 act-col tiles of 128

  const uint8_t* pA = x8p + (size_t)mt  * (KT1 * 16384) + tid * 16;
  const uint8_t* pB = wgp + (size_t)ntB * (KT1 * 16384) + tid * 16;

  i32x4 acc[8][4] = {};

#define STG1(t, s) do {                                        \
    uint8_t* l = sm + (s) * 32768 + tid * 16;                  \
    const uint8_t* aa = pA + (size_t)(t) * 16384;              \
    GLD16(aa, l);                                              \
    GLD16(aa + 8192, l + 8192);                                \
    const uint8_t* bb = pB + (size_t)(t) * 16384;              \
    GLD16(bb, l + 16384);                                      \
    GLD16(bb + 8192, l + 24576);                               \
  } while (0)

  STG1(0, 0); STG1(1, 1); STG1(2, 2);    // 12 loads in flight
  WVM(8); BAR();                          // tile 0 landed; 1,2 in flight

  for (int t = 0; t < KT1; ++t) {
    const int rem = KT1 - 1 - t;
    const uint8_t* b = sm + (t & 3) * 32768;
    uint8_t* lnx = sm + ((t + 3) & 3) * 32768 + tid * 16;
    // ---------- phase A: B-frags + A-low, stage next B ----------
    i32x4 bv[4], av[4];
#pragma unroll
    for (int n = 0; n < 4; ++n)
      bv[n] = *reinterpret_cast<const i32x4*>(b + bBase + n * 1024);
#pragma unroll
    for (int m = 0; m < 4; ++m)
      av[m] = *reinterpret_cast<const i32x4*>(b + aBase + m * 1024);
    if (rem >= 3) {
      const uint8_t* bb = pB + (size_t)(t + 3) * 16384;
      GLD16(bb, lnx + 16384);
      GLD16(bb + 8192, lnx + 24576);
    }
    BAR();
    LGKM0();
    __builtin_amdgcn_s_setprio(1);
#pragma unroll
    for (int m = 0; m < 4; ++m)
#pragma unroll
      for (int n = 0; n < 4; ++n)
        acc[m][n] = __builtin_amdgcn_mfma_i32_16x16x64_i8(
            av[m], bv[n], acc[m][n], 0, 0, 0);
    __builtin_amdgcn_s_setprio(0);
    // ---------- phase B: A-high, stage next A ----------
#pragma unroll
    for (int m = 0; m < 4; ++m)
      av[m] = *reinterpret_cast<const i32x4*>(b + aBase + (m + 4) * 1024);
    if (rem >= 3) {
      const uint8_t* aa = pA + (size_t)(t + 3) * 16384;
      GLD16(aa, lnx);
      GLD16(aa + 8192, lnx + 8192);
      WVM(8);                      // tile t+1 landed; t+2,t+3 in flight
    } else if (rem == 2) { WVM(4); }
    else if (rem == 1)   { WVM(0); }
    BAR();
    LGKM0();
    __builtin_amdgcn_s_setprio(1);
#pragma unroll
    for (int m = 0; m < 4; ++m)
#pragma unroll
      for (int n = 0; n < 4; ++n)
        acc[m + 4][n] = __builtin_amdgcn_mfma_i32_16x16x64_i8(
            av[m], bv[n], acc[m + 4][n], 0, 0, 0);
    __builtin_amdgcn_s_setprio(0);
  }
#undef STG1

  __syncthreads();                        // all K-loop LDS traffic retired
  // ---- fused epilogue: silu(gate)*up in registers + rowmax ----
  // acc[m][2p] = gate(row, col p), acc[m][2p+1] = up(row, col p):
  // col = ntB*128 + wgn*32 + p*16 + r15.
  float* smred = (float*)sm;              // [4 wgn][256 rows] = 4KB (slot 0)
  const int rq = (lane >> 4) << 2;
#pragma unroll
  for (int m = 0; m < 8; ++m) {
    float am[4] = {0.f, 0.f, 0.f, 0.f};
#pragma unroll
    for (int p = 0; p < 2; ++p) {
      const int colb = ntB * 128 + (wgn << 5) + (p << 4) + r15;
      const float gsc = wgs[colb];
      const float usc = wgs[INTER + colb];
#pragma unroll
      for (int r = 0; r < 4; ++r) {
        const int rowl = (wgm << 7) + m * 16 + rq + r;
        const int grow = mt * 256 + rowl;
        const float xr = xs[grow];
        const float g  = (float)acc[m][2 * p][r] * xr * gsc;
        const float uv = (float)acc[m][2 * p + 1][r] * xr * usc;
        const float a  = g / (1.f + __expf(-g)) * uv;
        act[(size_t)grow * INTER + colb] = f2bf(a);
        am[r] = fmaxf(am[r], __builtin_fabsf(a));
      }
    }
#pragma unroll
    for (int r = 0; r < 4; ++r)
#pragma unroll
      for (int off = 1; off < 16; off <<= 1)
        am[r] = fmaxf(am[r], __shfl_xor(am[r], off, 64));
    if (r15 == 0) {
#pragma unroll
      for (int r = 0; r < 4; ++r)
        smred[wgn * 256 + (wgm << 7) + m * 16 + rq + r] = am[r];
    }
  }
  __syncthreads();
  if (tid < 256) {
    const float vmx = fmaxf(fmaxf(smred[tid], smred[256 + tid]),
                            fmaxf(smred[512 + tid], smred[768 + tid]));
    atomicMax((int*)&mx[mt * 256 + tid], __float_as_int(vmx));
  }
}

// ---------------------------------------------------------------------------
// quant: q2 = clip(rint(act * 127/mx)) -> int8 FRAGMENT-MAJOR panel
// (PR=128, 8 frags/step, 16 panels x KT2 steps). No silu recompute.
// ---------------------------------------------------------------------------
__global__ __launch_bounds__(256) void quant_k(
    const unsigned short* __restrict__ act, const float* __restrict__ mx,
    uint8_t* __restrict__ q2p)
{
  const int u = blockIdx.x * 256 + threadIdx.x;
  const int l = u & 63;
  const int rest = u >> 6;
  const int f = rest & 7;                // 8 frags (PR=128)
  const int s = rest >> 3;
  const int mt = s / KT2;
  const int t = s - mt * KT2;
  const int row = mt * 128 + f * 16 + (l & 15);
  const int col = t * 64 + ((l >> 4) << 4);
  const unsigned short* ap = act + (size_t)row * INTER + col;
  const float inv = 127.0f / fmaxf(mx[row], 1e-30f);
  u16x8 a0 = *reinterpret_cast<const u16x8*>(ap);
  u16x8 a1 = *reinterpret_cast<const u16x8*>(ap + 8);
  i32x4 o;
#pragma unroll
  for (int qq = 0; qq < 4; ++qq) {
    uint32_t d = 0;
#pragma unroll
    for (int b = 0; b < 4; ++b) {
      const int j = qq * 4 + b;
      float af = bf2f((j < 8) ? a0[j] : a1[j - 8]);
      float rr = rintf(af * inv);
      rr = fminf(fmaxf(rr, -127.f), 127.f);
      d |= ((uint32_t)((int)rr & 255)) << (8 * b);
    }
    o[qq] = (int)d;
  }
  *reinterpret_cast<i32x4*>(q2p + (size_t)u * 16) = o;
}

// ---------------------------------------------------------------------------
// GEMM2 (r18-frozen): 128x256 tile, 8 waves, BK=64B, 4-slot 24KB ring,
// distance-3, vmcnt 6/3/0, 2-phase K-step, fragment-major LDS.
// ---------------------------------------------------------------------------
__global__ __launch_bounds__(512, 2) void gemm2_k(
    const uint8_t* __restrict__ q2p, const uint8_t* __restrict__ wdp,
    const float* __restrict__ mx, const float* __restrict__ wds,
    float* __restrict__ out)
{
  __shared__ uint8_t sm[98304];
  const int tid = threadIdx.x;
  const int lane = tid & 63, wid = tid >> 6;
  const int wgm = wid >> 2, wgn = wid & 3;
  const int r15 = lane & 15;
  const int l16 = lane * 16;
  const int aBase = (wgm << 12) + l16;            // wgm*4096
  const int bBase = 8192 + (wgn << 12) + l16;     // 8192 + wgn*4096

  const int bid = blockIdx.x;
  const int v = (bid & 7) * 32 + (bid >> 3);   // XCD-chunked, bijective
  const int nt = v >> 4, mt = v & 15;

  const uint8_t* pA = q2p + (size_t)mt * (KT2 * 8192)  + tid * 16;
  const uint8_t* pB = wdp + (size_t)nt * (KT2 * 16384) + tid * 16;

  i32x4 acc[4][4] = {};

#define STG2(t, s) do {                                        \
    uint8_t* l = sm + (s) * 24576 + tid * 16;                  \
    GLD16(pA + (size_t)(t) * 8192, l);                         \
    const uint8_t* bb = pB + (size_t)(t) * 16384;              \
    GLD16(bb, l + 8192);                                       \
    GLD16(bb + 8192, l + 16384);                               \
  } while (0)

  STG2(0, 0); STG2(1, 1); STG2(2, 2);    // 9 loads in flight
  WVM(6); BAR();

  for (int t = 0; t < KT2; ++t) {
    const int rem = KT2 - 1 - t;
    const uint8_t* b = sm + (t & 3) * 24576;
    uint8_t* lnx = sm + ((t + 3) & 3) * 24576 + tid * 16;
    // ---------- phase A ----------
    i32x4 bv[4], av[2];
#pragma unroll
    for (int n = 0; n < 4; ++n)
      bv[n] = *reinterpret_cast<const i32x4*>(b + bBase + n * 1024);
#pragma unroll
    for (int m = 0; m < 2; ++m)
      av[m] = *reinterpret_cast<const i32x4*>(b + aBase + m * 1024);
    if (rem >= 3) {
      const uint8_t* bb = pB + (size_t)(t + 3) * 16384;
      GLD16(bb, lnx + 8192);
      GLD16(bb + 8192, lnx + 16384);
    }
    BAR();
    LGKM0();
    __builtin_amdgcn_s_setprio(1);
#pragma unroll
    for (int m = 0; m < 2; ++m)
#pragma unroll
      for (int n = 0; n < 4; ++n)
        acc[m][n] = __builtin_amdgcn_mfma_i32_16x16x64_i8(
            av[m], bv[n], acc[m][n], 0, 0, 0);
    __builtin_amdgcn_s_setprio(0);
    // ---------- phase B ----------
#pragma unroll
    for (int m = 0; m < 2; ++m)
      av[m] = *reinterpret_cast<const i32x4*>(b + aBase + (m + 2) * 1024);
    if (rem >= 3) {
      GLD16(pA + (size_t)(t + 3) * 8192, lnx);
      WVM(6);
    } else if (rem == 2) { WVM(3); }
    else if (rem == 1)   { WVM(0); }
    BAR();
    LGKM0();
    __builtin_amdgcn_s_setprio(1);
#pragma unroll
    for (int m = 0; m < 2; ++m)
#pragma unroll
      for (int n = 0; n < 4; ++n)
        acc[m + 2][n] = __builtin_amdgcn_mfma_i32_16x16x64_i8(
            av[m], bv[n], acc[m + 2][n], 0, 0, 0);
    __builtin_amdgcn_s_setprio(0);
  }
#undef STG2

  const int rq = (lane >> 4) << 2;
#pragma unroll
  for (int m = 0; m < 4; ++m) {
#pragma unroll
    for (int r = 0; r < 4; ++r) {
      const int rowl = (wgm << 6) + m * 16 + rq + r;
      const int grow = mt * 128 + rowl;
      const float s2 = mx[grow] * (1.0f / 127.0f);
      float* op = out + (size_t)grow * HID + nt * 256 + (wgn << 6) + r15;
      const float* wp = wds + nt * 256 + (wgn << 6) + r15;
#pragma unroll
      for (int n = 0; n < 4; ++n)
        op[n * 16] = (float)acc[m][n][r] * s2 * wp[n * 16];
    }
  }
}

// ---------------------------------------------------------------------------
extern "C" void kernel_launch(void* const* d_in, const int* in_sizes, int n_in,
                              void* d_out, int out_size, void* d_ws, size_t ws_size,
                              hipStream_t stream)
{
  const int*   x_q = (const int*)d_in[0];
  const float* xs  = (const float*)d_in[1];
  const int*   wg  = (const int*)d_in[2];
  const float* wgs = (const float*)d_in[3];
  const int*   wd  = (const int*)d_in[4];
  const float* wds = (const float*)d_in[5];
  float* out = (float*)d_out;

  uint8_t* ws = (uint8_t*)d_ws;
  uint8_t* x8p = ws;                                         //   8,388,608
  uint8_t* wgp = x8p + 8388608;                              //  90,177,536
  uint8_t* wdp = wgp + 90177536;                             //  45,088,768
  unsigned short* act = (unsigned short*)(wdp + 45088768);   //  45,088,768
  float* mx = (float*)((uint8_t*)act + 45088768);            //       8,192
  uint8_t* q2p = (uint8_t*)mx + 8192;                        //  22,544,384
  // total ~211.3 MB

  zero_mx<<<2, 1024, 0, stream>>>(mx);
  pack_frag<<<2048, 256, 0, stream>>>(x_q, x8p, 8, KT1, HID);    // A panels
  pack_gufrag<<<22016, 256, 0, stream>>>(wg, wgp);               // B1 interleaved
  pack_frag<<<11008, 256, 0, stream>>>(wd, wdp, 8, KT2, INTER);  // B2 panels

  gemm1_k<<<688, 512, 0, stream>>>(x8p, wgp, xs, wgs, act, mx);
  quant_k<<<5504, 256, 0, stream>>>(act, mx, q2p);
  gemm2_k<<<256, 512, 0, stream>>>(q2p, wdp, mx, wds, out);
}